// Round 16
// baseline (212.933 us; speedup 1.0000x reference)
//
#include <hip/hip_runtime.h>
#include <hip/hip_bf16.h>
#include <hip/hip_cooperative_groups.h>

namespace cg = cooperative_groups;

#define NB 4
#define NN 2048
#define ND 512
#define NE 16
#define NH 1024
#define CAP 256
#define NTOK (NB*NN)

typedef __attribute__((ext_vector_type(8))) short bf16x8;
typedef __attribute__((ext_vector_type(4))) float f32x4;
typedef __attribute__((ext_vector_type(8))) unsigned short u16x8;

__device__ __forceinline__ void gload16(const void* gsrc, void* lds) {
    __builtin_amdgcn_global_load_lds((const __attribute__((address_space(1))) void*)gsrc,
                                     (__attribute__((address_space(3))) void*)lds, 16, 0, 0);
}
__device__ __forceinline__ unsigned short f2bf(float f) {
    union { __hip_bfloat16 b; unsigned short u; } v; v.b = __float2bfloat16(f); return v.u;
}

// One cooperative kernel, 256 blocks x 512 threads, phases split by grid.sync().
// LDS arena (max = expert): Ash 64K | Bsh 2x32K | u_lds 4K | sbuf 2K | toks 1K = 137472 B
__global__ __launch_bounds__(512, 1) void moe_mega_kernel(
        const float* __restrict__ X, const float* __restrict__ probs,
        const float* __restrict__ W1, const float* __restrict__ b1,
        const float* __restrict__ Wg, const float* __restrict__ We1,
        const float* __restrict__ We2, const float* __restrict__ W3,
        const float* __restrict__ b3, const float* __restrict__ W4,
        const float* __restrict__ b4,
        unsigned short* __restrict__ Xbf, unsigned short* __restrict__ hbf,
        unsigned short* __restrict__ W1B, unsigned short* __restrict__ We1B,
        float* __restrict__ WcT, float* __restrict__ u, float* __restrict__ zbuf,
        int* __restrict__ idx1a, int* __restrict__ idx2a,
        float* __restrict__ g1a, float* __restrict__ g2a,
        int* __restrict__ slot_token, float* __restrict__ out) {
    __shared__ __align__(16) char SM[137472];
    cg::grid_group grid = cg::this_grid();
    const int tid = threadIdx.x;
    const int w = tid >> 6, l = tid & 63;
    const int bid = blockIdx.x;

    // ================= P0: weight prep =================
    {
        float* tile = (float*)SM;                       // 64KB [64 d][256 h]
        auto do_unit = [&](const float* src, int C, size_t soff,
                           unsigned short* dstp, size_t drow) {
            __syncthreads();                            // tile reuse guard
            #pragma unroll
            for (int i = 0; i < 8; ++i) {
                int idx = tid + i * 512;                // 4096 chunks of 16B
                int d = idx >> 6, c = idx & 63;
                gload16(src + soff + (size_t)d * C + c * 4, (char*)SM + idx * 16);
            }
            __syncthreads();
            const int hl = tid & 255, dseg = tid >> 8;
            float v[32];
            #pragma unroll
            for (int j = 0; j < 32; ++j) v[j] = tile[(dseg * 32 + j) * 256 + hl];
            unsigned short* dr = dstp + (drow + hl) * 64 + dseg * 32;
            #pragma unroll
            for (int q = 0; q < 4; ++q) {
                u16x8 o;
                #pragma unroll
                for (int j = 0; j < 8; ++j) o[j] = f2bf(v[q * 8 + j]);
                *(u16x8*)(dr + q * 8) = o;
            }
        };
        #pragma unroll
        for (int q2 = 0; q2 < 2; ++q2) {                // 2 We1 units per block
            int unit = bid * 2 + q2;                    // 0..511
            int e = unit >> 5, rem = unit & 31;
            int dblk = rem >> 2, hq = rem & 3;
            do_unit(We1, NH, (size_t)e * ND * NH + (size_t)(dblk * 64) * NH + hq * 256,
                    We1B, (size_t)(e * 8 + dblk) * NH + hq * 256);
        }
        if (bid < 16) {                                 // W1 units on blocks 0..15
            int dblk = bid >> 1, hq = bid & 1;
            do_unit(W1, ND, (size_t)(dblk * 64) * ND + hq * 256,
                    W1B, (size_t)(dblk * 512 + hq * 256));
        }
        if (bid == 200 && tid < 256) zbuf[tid] = 0.f;
        if (bid >= 8 && bid < 72) {                     // WcT wave-per-d, d = (bid-8)*8+w
            const int d = (bid - 8) * 8 + w;
            float a0 = 0.f, a1 = 0.f, a2 = 0.f, a3 = 0.f, a4 = 0.f, a5 = 0.f, a6 = 0.f, a7 = 0.f;
            float a8 = 0.f, a9 = 0.f, aA = 0.f, aB = 0.f, aC = 0.f, aD = 0.f, aE = 0.f, aF = 0.f;
            #pragma unroll
            for (int ch = 0; ch < 8; ++ch) {
                float x = W1[(size_t)d * ND + ch * 64 + l];
                const float4* wg4 = (const float4*)(Wg + (size_t)(ch * 64 + l) * NE);
                float4 g0 = wg4[0], g1 = wg4[1], g2 = wg4[2], g3 = wg4[3];
                a0 = fmaf(x, g0.x, a0); a1 = fmaf(x, g0.y, a1); a2 = fmaf(x, g0.z, a2); a3 = fmaf(x, g0.w, a3);
                a4 = fmaf(x, g1.x, a4); a5 = fmaf(x, g1.y, a5); a6 = fmaf(x, g1.z, a6); a7 = fmaf(x, g1.w, a7);
                a8 = fmaf(x, g2.x, a8); a9 = fmaf(x, g2.y, a9); aA = fmaf(x, g2.z, aA); aB = fmaf(x, g2.w, aB);
                aC = fmaf(x, g3.x, aC); aD = fmaf(x, g3.y, aD); aE = fmaf(x, g3.z, aE); aF = fmaf(x, g3.w, aF);
            }
            float accs[16] = {a0, a1, a2, a3, a4, a5, a6, a7, a8, a9, aA, aB, aC, aD, aE, aF};
            #pragma unroll
            for (int off = 32; off >= 1; off >>= 1)
                #pragma unroll
                for (int e = 0; e < 16; ++e) accs[e] += __shfl_xor(accs[e], off);
            #pragma unroll
            for (int e = 0; e < 16; ++e)
                if (l == e) WcT[e * ND + d] = accs[e];
        }
        {                                               // u: 64 rows per block (all blocks)
            __syncthreads();                            // done reading tile
            float* vvs = (float*)SM;                    // 2KB
            {
                float s0 = 0.f;
                #pragma unroll
                for (int j = 0; j < 4; ++j) s0 += W3[tid * 4 + j] * W4[j];
                vvs[tid] = s0;
            }
            __syncthreads();
            const float4* vv4 = (const float4*)vvs;
            const float4 v0 = vv4[l], v1 = vv4[l + 64];
            float sums[8];
            #pragma unroll
            for (int i = 0; i < 8; ++i) {
                int gr = bid * 64 + w * 8 + i;
                const float4* row = (const float4*)(We2 + (size_t)gr * ND);
                float4 p0 = row[l], p1 = row[l + 64];
                sums[i] = p0.x * v0.x + p0.y * v0.y + p0.z * v0.z + p0.w * v0.w
                        + p1.x * v1.x + p1.y * v1.y + p1.z * v1.z + p1.w * v1.w;
            }
            #pragma unroll
            for (int off = 32; off >= 1; off >>= 1)
                #pragma unroll
                for (int i = 0; i < 8; ++i) sums[i] += __shfl_xor(sums[i], off);
            if (l == 0) {
                int gr0 = bid * 64 + w * 8;
                #pragma unroll
                for (int i = 0; i < 8; ++i) u[gr0 + i] = sums[i];
            }
        }
    }
    grid.sync();
    // ================= P1: gating (32 tokens/block) =================
    {
        float* wc = (float*)SM;                         // 32KB
        #pragma unroll
        for (int i = 0; i < 16; ++i) wc[tid + 512 * i] = WcT[tid + 512 * i];
        float c0v = b4[0];
        #pragma unroll
        for (int j = 0; j < 4; ++j) c0v += b3[j] * W4[j];
        __syncthreads();
        const float4* wc4 = (const float4*)wc;
        for (int j = 0; j < 4; ++j) {
            int tok = bid * 32 + j * 8 + w;
            const float4* xrow = (const float4*)(X + (size_t)tok * ND);
            float4 x0 = xrow[l], x1 = xrow[l + 64];
            {   // side output: bf16 X
                ushort4 o0, o1;
                o0.x = f2bf(x0.x); o0.y = f2bf(x0.y); o0.z = f2bf(x0.z); o0.w = f2bf(x0.w);
                o1.x = f2bf(x1.x); o1.y = f2bf(x1.y); o1.z = f2bf(x1.z); o1.w = f2bf(x1.w);
                *(ushort4*)(Xbf + (size_t)tok * ND + 4 * l) = o0;
                *(ushort4*)(Xbf + (size_t)tok * ND + 256 + 4 * l) = o1;
            }
            float acc[NE];
            #pragma unroll
            for (int e = 0; e < NE; ++e) {
                float4 w0 = wc4[e * 128 + l], w1 = wc4[e * 128 + l + 64];
                acc[e] = x0.x * w0.x + x0.y * w0.y + x0.z * w0.z + x0.w * w0.w
                       + x1.x * w1.x + x1.y * w1.y + x1.z * w1.z + x1.w * w1.w;
            }
            #pragma unroll
            for (int off = 32; off >= 1; off >>= 1)
                #pragma unroll
                for (int e = 0; e < NE; ++e) acc[e] += __shfl_xor(acc[e], off);
            if (l == 0) {
                float m = acc[0];
                #pragma unroll
                for (int e = 1; e < NE; ++e) m = fmaxf(m, acc[e]);
                float raw[NE]; float s = 0.f;
                #pragma unroll
                for (int e = 0; e < NE; ++e) { raw[e] = expf(acc[e] - m); s += raw[e]; }
                #pragma unroll
                for (int e = 0; e < NE; ++e) raw[e] = raw[e] / s;
                int i1 = 0; float g1 = raw[0];
                #pragma unroll
                for (int e = 1; e < NE; ++e) if (raw[e] > g1) { g1 = raw[e]; i1 = e; }
                int i2 = -1; float g2 = -1.f;
                #pragma unroll
                for (int e = 0; e < NE; ++e) if (e != i1 && raw[e] > g2) { g2 = raw[e]; i2 = e; }
                float denom = g1 + g2 + 1e-9f;
                float g1n = g1 / denom, g2n = g2 / denom;
                bool flag = probs[tok] < (g2n / 0.2f);
                idx1a[tok] = i1;
                idx2a[tok] = flag ? i2 : -1;
                g1a[tok] = g1n;
                g2a[tok] = g2n;
                out[tok] = c0v;
            }
        }
    }
    grid.sync();
    // ================= P2: scan (blocks 0..63) =================
    if (bid < 64) {
        const int b = bid >> 4, e = bid & 15;
        int* cnt1 = (int*)SM;
        int* cnt2 = cnt1 + 8;
        int* slot = slot_token + (e * NB + b) * CAP;
        const unsigned long long below = (l == 0) ? 0ull : ((1ull << l) - 1ull);
        const int base0 = w * 256;
        int c1 = 0, c2 = 0;
        #pragma unroll
        for (int it = 0; it < 4; ++it) {
            int n = base0 + it * 64 + l;
            c1 += __popcll(__ballot(idx1a[b * NN + n] == e));
            c2 += __popcll(__ballot(idx2a[b * NN + n] == e));
        }
        if (l == 0) { cnt1[w] = c1; cnt2[w] = c2; }
        __syncthreads();
        int b1c = 0, t1 = 0, b2c = 0, t2 = 0;
        #pragma unroll
        for (int i = 0; i < 8; ++i) {
            int v1 = cnt1[i], v2 = cnt2[i];
            if (i < w) { b1c += v1; b2c += v2; }
            t1 += v1; t2 += v2;
        }
        const int start2 = (t1 < CAP) ? t1 : CAP;
        int c = b1c;
        #pragma unroll
        for (int it = 0; it < 4; ++it) {
            int n = base0 + it * 64 + l;
            bool p = (idx1a[b * NN + n] == e);
            unsigned long long m = __ballot(p);
            int pre = __popcll(m & below);
            if (p) { int pos = c + pre; if (pos < CAP) slot[pos] = n; }
            c += __popcll(m);
        }
        c = start2 + b2c;
        #pragma unroll
        for (int it = 0; it < 4; ++it) {
            int n = base0 + it * 64 + l;
            bool p = (idx2a[b * NN + n] == e);
            unsigned long long m = __ballot(p);
            int pre = __popcll(m & below);
            if (p) { int pos = c + pre; if (pos < CAP) slot[pos] = n | (1 << 30); }
            c += __popcll(m);
        }
        int nfill = start2 + t2; nfill = (nfill < CAP) ? nfill : CAP;
        for (int i = nfill + tid; i < CAP; i += 512) slot[i] = -1;
    }
    grid.sync();
    // ================= P3: linear1 (all 256 blocks) =================
    {
        const int m0 = (bid >> 2) * 128, n0 = (bid & 3) * 128;
        const int wm = w >> 1, wn = w & 1;
        const int lr = l & 15, lk = l >> 4;
        char* Ash0 = SM;                                // 2 x 16384
        char* Bsh0 = SM + 32768;                        // 2 x 16384
        auto stage = [&](int Ks, int buf) {
            #pragma unroll
            for (int i = 0; i < 2; ++i) {
                int o = i * 8192 + tid * 16;
                int r = o >> 7, bb = o & 127;
                int sb = bb ^ ((r & 7) << 4);
                gload16((const char*)Xbf + ((size_t)(m0 + r) * ND + Ks * 64) * 2 + sb,
                        Ash0 + buf * 16384 + i * 8192 + w * 1024);
                gload16((const char*)W1B + ((size_t)(Ks * 512 + n0 + r) * 64) * 2 + sb,
                        Bsh0 + buf * 16384 + i * 8192 + w * 1024);
            }
        };
        f32x4 acc[2][4] = {};
        __syncthreads();
        stage(0, 0);
        __syncthreads();
        for (int Ks = 0; Ks < 8; ++Ks) {
            int buf = Ks & 1;
            if (Ks < 7) stage(Ks + 1, buf ^ 1);
            #pragma unroll
            for (int k32 = 0; k32 < 2; ++k32) {
                int kb = (k32 * 32 + 8 * lk) * 2;
                bf16x8 a[2], bfr[4];
                #pragma unroll
                for (int mi = 0; mi < 2; ++mi) {
                    int row = wm * 32 + mi * 16 + lr;
                    a[mi] = *(const bf16x8*)(Ash0 + buf * 16384 + row * 128 + (kb ^ ((row & 7) << 4)));
                }
                #pragma unroll
                for (int ni = 0; ni < 4; ++ni) {
                    int row = wn * 64 + ni * 16 + lr;
                    bfr[ni] = *(const bf16x8*)(Bsh0 + buf * 16384 + row * 128 + (kb ^ ((row & 7) << 4)));
                }
                #pragma unroll
                for (int mi = 0; mi < 2; ++mi)
                    #pragma unroll
                    for (int ni = 0; ni < 4; ++ni)
                        acc[mi][ni] = __builtin_amdgcn_mfma_f32_16x16x32_bf16(a[mi], bfr[ni], acc[mi][ni], 0, 0, 0);
            }
            __syncthreads();
        }
        #pragma unroll
        for (int mi = 0; mi < 2; ++mi)
            #pragma unroll
            for (int ni = 0; ni < 4; ++ni) {
                int col = n0 + wn * 64 + ni * 16 + lr;
                float bb1 = b1[col];
                #pragma unroll
                for (int r = 0; r < 4; ++r) {
                    int m = m0 + wm * 32 + mi * 16 + lk * 4 + r;
                    hbf[(size_t)m * ND + col] = f2bf(acc[mi][ni][r] + bb1);
                }
            }
    }
    grid.sync();
    // ================= P4: expert (all 256 blocks) =================
    {
        char* Ash = SM;                                 // 64K
        char* Bsh0 = SM + 65536;                        // 2 x 32768
        float* u_lds = (float*)(SM + 131072);           // 4K
        float* sbuf = (float*)(SM + 135168);            // 8 x 64 floats
        int* toks = (int*)(SM + 137216);                // 64 ints
        const int lr = l & 15, lk = l >> 4;
        const int e = (bid & 7) | ((bid >> 7) << 3);
        const int chunk = (bid >> 3) & 15;
        const int b = chunk >> 2, c0 = (chunk & 3) * 64;

        if (tid < 64) toks[tid] = slot_token[(e * NB + b) * CAP + c0 + tid];
        u_lds[tid] = u[e * NH + tid];
        u_lds[tid + 512] = u[e * NH + tid + 512];
        __syncthreads();
        #pragma unroll
        for (int i = 0; i < 8; ++i) {
            int r = i * 8 + w;
            int t = toks[r];
            int tok = t & 2047;
            int sb = (l * 16) ^ ((r & 7) << 4);
            const char* src = (t >= 0) ? ((const char*)hbf + ((size_t)(b * NN + tok) * ND) * 2 + sb)
                                       : ((const char*)zbuf + sb);
            gload16(src, Ash + i * 8192 + w * 1024);
        }
        auto stageB = [&](int s, int buf) {
            int Hc = s >> 4, Ks = s & 15;
            const size_t base = ((size_t)(e * 8 + (Ks >> 1)) * NH + Hc * 512) * 64 + (Ks & 1) * 32;
            #pragma unroll
            for (int i = 0; i < 4; ++i) {
                int r = i * 128 + w * 16 + (l >> 2);
                int swzr = ((r >> 1) & 3) << 4;
                int ebyte = ((l & 3) * 16) ^ swzr;
                gload16((const char*)We1B + (base + (size_t)r * 64) * 2 + ebyte,
                        Bsh0 + buf * 32768 + i * 8192 + w * 1024);
            }
        };
        f32x4 acc[4][4] = {};
        float srow[4][4] = {};
        stageB(0, 0);
        __syncthreads();
        for (int s = 0; s < 32; ++s) {
            int buf = s & 1;
            if (s < 31) stageB(s + 1, buf ^ 1);
            int Ks = s & 15;
            bf16x8 a[4], bb[4];
            #pragma unroll
            for (int mi = 0; mi < 4; ++mi) {
                int row = mi * 16 + lr;
                int kb = (Ks * 64 + lk * 16) ^ ((row & 7) << 4);
                a[mi] = *(const bf16x8*)(Ash + row * 1024 + kb);
            }
            #pragma unroll
            for (int ni = 0; ni < 4; ++ni) {
                int row = w * 64 + ni * 16 + lr;
                int kb = (lk * 16) ^ (((row >> 1) & 3) << 4);
                bb[ni] = *(const bf16x8*)(Bsh0 + buf * 32768 + row * 64 + kb);
            }
            #pragma unroll
            for (int mi = 0; mi < 4; ++mi)
                #pragma unroll
                for (int ni = 0; ni < 4; ++ni)
                    acc[mi][ni] = __builtin_amdgcn_mfma_f32_16x16x32_bf16(a[mi], bb[ni], acc[mi][ni], 0, 0, 0);
            if ((s & 15) == 15) {
                int Hc = s >> 4;
                #pragma unroll
                for (int ni = 0; ni < 4; ++ni) {
                    float uu = u_lds[Hc * 512 + w * 64 + ni * 16 + lr];
                    #pragma unroll
                    for (int mi = 0; mi < 4; ++mi)
                        #pragma unroll
                        for (int r = 0; r < 4; ++r) {
                            float x = acc[mi][ni][r];
                            x = (x > 0.f) ? x : 0.01f * x;
                            srow[mi][r] = fmaf(x, uu, srow[mi][r]);
                            acc[mi][ni][r] = 0.f;
                        }
                }
            }
            __syncthreads();
        }
        #pragma unroll
        for (int off = 1; off < 16; off <<= 1)
            #pragma unroll
            for (int mi = 0; mi < 4; ++mi)
                #pragma unroll
                for (int r = 0; r < 4; ++r)
                    srow[mi][r] += __shfl_xor(srow[mi][r], off);
        if (lr == 0) {
            #pragma unroll
            for (int mi = 0; mi < 4; ++mi)
                #pragma unroll
                for (int r = 0; r < 4; ++r)
                    sbuf[w * 64 + mi * 16 + lk * 4 + r] = srow[mi][r];
        }
        __syncthreads();
        if (tid < 64) {
            float s = 0.f;
            #pragma unroll
            for (int q = 0; q < 8; ++q) s += sbuf[q * 64 + tid];
            int v = toks[tid];
            if (v >= 0) {
                int tok = v & 2047;
                float g = (v & (1 << 30)) ? g2a[b * NN + tok] : g1a[b * NN + tok];
                atomicAdd(out + b * NN + tok, s * g);
            }
        }
    }
}

extern "C" void kernel_launch(void* const* d_in, const int* in_sizes, int n_in,
                              void* d_out, int out_size, void* d_ws, size_t ws_size,
                              hipStream_t stream) {
    const float* X    = (const float*)d_in[0];
    const float* probs= (const float*)d_in[1];
    const float* W1   = (const float*)d_in[2];
    const float* b1   = (const float*)d_in[3];
    const float* Wg   = (const float*)d_in[4];
    const float* We1  = (const float*)d_in[5];
    const float* We2  = (const float*)d_in[6];
    const float* W3   = (const float*)d_in[7];
    const float* b3   = (const float*)d_in[8];
    const float* W4   = (const float*)d_in[9];
    const float* b4   = (const float*)d_in[10];
    float* out = (float*)d_out;

    char* ws = (char*)d_ws;
    size_t off = 0;
    auto alloc = [&](size_t bytes) { void* p = ws + off; off += (bytes + 255) & ~(size_t)255; return p; };
    unsigned short* Xbf  = (unsigned short*)alloc((size_t)NTOK * ND * 2);     // 8 MB
    unsigned short* hbf  = (unsigned short*)alloc((size_t)NTOK * ND * 2);     // 8 MB
    unsigned short* W1B  = (unsigned short*)alloc((size_t)ND * ND * 2);       // 512 KB
    unsigned short* We1B = (unsigned short*)alloc((size_t)NE * NH * ND * 2);  // 16 MB
    float* WcT     = (float*)alloc(NE * ND * 4);
    float* u       = (float*)alloc(NE * NH * 4);
    float* zbuf    = (float*)alloc(1024);
    int*   idx1a   = (int*)alloc(NTOK * 4);
    int*   idx2a   = (int*)alloc(NTOK * 4);
    float* g1a     = (float*)alloc(NTOK * 4);
    float* g2a     = (float*)alloc(NTOK * 4);
    int*   slot_tok= (int*)alloc(NE * NB * CAP * 4);
    (void)ws_size; (void)in_sizes; (void)n_in; (void)out_size;

    void* args[] = {&X, &probs, &W1, &b1, &Wg, &We1, &We2, &W3, &b3, &W4, &b4,
                    &Xbf, &hbf, &W1B, &We1B, &WcT, &u, &zbuf,
                    &idx1a, &idx2a, &g1a, &g2a, &slot_tok, &out};
    hipLaunchCooperativeKernel(reinterpret_cast<void*>(moe_mega_kernel),
                               dim3(256), dim3(512), args, 0, stream);
}

// Round 17
// 82.029 us; speedup vs baseline: 2.5958x; 2.5958x over previous
//
#include <hip/hip_runtime.h>
#include <hip/hip_bf16.h>

#define NB 4
#define NN 2048
#define ND 512
#define NE 16
#define NH 1024
#define CAP 256
#define NTOK (NB*NN)

typedef __attribute__((ext_vector_type(8))) short bf16x8;
typedef __attribute__((ext_vector_type(4))) float f32x4;
typedef __attribute__((ext_vector_type(8))) unsigned short u16x8;

__device__ __forceinline__ void gload16(const void* gsrc, void* lds) {
    __builtin_amdgcn_global_load_lds((const __attribute__((address_space(1))) void*)gsrc,
                                     (__attribute__((address_space(3))) void*)lds, 16, 0, 0);
}
__device__ __forceinline__ unsigned short f2bf(float f) {
    union { __hip_bfloat16 b; unsigned short u; } v; v.b = __float2bfloat16(f); return v.u;
}

// ------- kernel A (tiny critical prefix): WcT + W1B + zbuf -------
__global__ __launch_bounds__(256) void prep_w_kernel(const float* __restrict__ W1,
                                                     const float* __restrict__ Wg,
                                                     unsigned short* __restrict__ W1B,
                                                     float* __restrict__ WcT,
                                                     float* __restrict__ zbuf) {
    const int tid = threadIdx.x;
    int bid = blockIdx.x;
    if (bid < 128) {                                    // ---- WcT: wave-per-d
        if (bid == 0) zbuf[tid] = 0.f;
        const int w = tid >> 6, l = tid & 63;
        const int d = bid * 4 + w;
        float a0 = 0.f, a1 = 0.f, a2 = 0.f, a3 = 0.f, a4 = 0.f, a5 = 0.f, a6 = 0.f, a7 = 0.f;
        float a8 = 0.f, a9 = 0.f, aA = 0.f, aB = 0.f, aC = 0.f, aD = 0.f, aE = 0.f, aF = 0.f;
        #pragma unroll
        for (int ch = 0; ch < 8; ++ch) {
            float x = W1[(size_t)d * ND + ch * 64 + l];
            const float4* wg4 = (const float4*)(Wg + (size_t)(ch * 64 + l) * NE);
            float4 g0 = wg4[0], g1 = wg4[1], g2 = wg4[2], g3 = wg4[3];
            a0 = fmaf(x, g0.x, a0); a1 = fmaf(x, g0.y, a1); a2 = fmaf(x, g0.z, a2); a3 = fmaf(x, g0.w, a3);
            a4 = fmaf(x, g1.x, a4); a5 = fmaf(x, g1.y, a5); a6 = fmaf(x, g1.z, a6); a7 = fmaf(x, g1.w, a7);
            a8 = fmaf(x, g2.x, a8); a9 = fmaf(x, g2.y, a9); aA = fmaf(x, g2.z, aA); aB = fmaf(x, g2.w, aB);
            aC = fmaf(x, g3.x, aC); aD = fmaf(x, g3.y, aD); aE = fmaf(x, g3.z, aE); aF = fmaf(x, g3.w, aF);
        }
        float accs[16] = {a0, a1, a2, a3, a4, a5, a6, a7, a8, a9, aA, aB, aC, aD, aE, aF};
        #pragma unroll
        for (int off = 32; off >= 1; off >>= 1)
            #pragma unroll
            for (int e = 0; e < 16; ++e) accs[e] += __shfl_xor(accs[e], off);
        #pragma unroll
        for (int e = 0; e < 16; ++e)
            if (l == e) WcT[e * ND + d] = accs[e];
        return;
    }
    bid -= 128;
    {                                                   // ---- W1B transpose, 64 d/thread
        int dblk = bid >> 1, hblk = bid & 1;
        const float* src = W1 + (size_t)(dblk * 64) * ND + hblk * 256 + tid;
        unsigned short* dst = W1B + (size_t)(dblk * 512 + hblk * 256 + tid) * 64;
        float v[64];
        #pragma unroll
        for (int j = 0; j < 64; ++j) v[j] = src[(size_t)j * ND];
        #pragma unroll
        for (int q = 0; q < 8; ++q) {
            u16x8 o;
            #pragma unroll
            for (int j = 0; j < 8; ++j) o[j] = f2bf(v[q * 8 + j]);
            *(u16x8*)(dst + q * 8) = o;
        }
    }
}

// ------- kernel B: gating (512) + We1^T (256) + u (256), all 256-thread -------
__global__ __launch_bounds__(256) void gating_stream_kernel(const float* __restrict__ X,
                                                            const float* __restrict__ WcT,
                                                            const float* __restrict__ probs,
                                                            const float* __restrict__ b3,
                                                            const float* __restrict__ W4,
                                                            const float* __restrict__ b4,
                                                            const float* __restrict__ We1,
                                                            const float* __restrict__ We2,
                                                            const float* __restrict__ W3,
                                                            unsigned short* __restrict__ Xbf,
                                                            unsigned short* __restrict__ We1B,
                                                            float* __restrict__ u,
                                                            int* __restrict__ idx1a, int* __restrict__ idx2a,
                                                            float* __restrict__ g1a, float* __restrict__ g2a,
                                                            float* __restrict__ out) {
    __shared__ float wc[NE * ND];           // 32KB (u section aliases wc[0..511])
    const int tid = threadIdx.x;
    int bid = blockIdx.x;
    const int w = tid >> 6, l = tid & 63;
    if (bid < 512) {                                    // ======== gating ========
        #pragma unroll
        for (int i = 0; i < 32; ++i) wc[tid + 256 * i] = WcT[tid + 256 * i];
        float c0v = b4[0];
        #pragma unroll
        for (int j = 0; j < 4; ++j) c0v += b3[j] * W4[j];
        __syncthreads();
        const float4* wc4 = (const float4*)wc;
        for (int j = 0; j < 4; ++j) {
            int tok = bid * 16 + j * 4 + w;
            const float4* xrow = (const float4*)(X + (size_t)tok * ND);
            float4 x0 = xrow[l], x1 = xrow[l + 64];
            {   // side output: bf16 X
                ushort4 o0, o1;
                o0.x = f2bf(x0.x); o0.y = f2bf(x0.y); o0.z = f2bf(x0.z); o0.w = f2bf(x0.w);
                o1.x = f2bf(x1.x); o1.y = f2bf(x1.y); o1.z = f2bf(x1.z); o1.w = f2bf(x1.w);
                *(ushort4*)(Xbf + (size_t)tok * ND + 4 * l) = o0;
                *(ushort4*)(Xbf + (size_t)tok * ND + 256 + 4 * l) = o1;
            }
            float acc[NE];
            #pragma unroll
            for (int e = 0; e < NE; ++e) {
                float4 w0 = wc4[e * 128 + l], w1 = wc4[e * 128 + l + 64];
                acc[e] = x0.x * w0.x + x0.y * w0.y + x0.z * w0.z + x0.w * w0.w
                       + x1.x * w1.x + x1.y * w1.y + x1.z * w1.z + x1.w * w1.w;
            }
            #pragma unroll
            for (int off = 32; off >= 1; off >>= 1)
                #pragma unroll
                for (int e = 0; e < NE; ++e) acc[e] += __shfl_xor(acc[e], off);

            if (l == 0) {
                float m = acc[0];
                #pragma unroll
                for (int e = 1; e < NE; ++e) m = fmaxf(m, acc[e]);
                float raw[NE]; float s = 0.f;
                #pragma unroll
                for (int e = 0; e < NE; ++e) { raw[e] = expf(acc[e] - m); s += raw[e]; }
                #pragma unroll
                for (int e = 0; e < NE; ++e) raw[e] = raw[e] / s;
                int i1 = 0; float g1 = raw[0];
                #pragma unroll
                for (int e = 1; e < NE; ++e) if (raw[e] > g1) { g1 = raw[e]; i1 = e; }
                int i2 = -1; float g2 = -1.f;
                #pragma unroll
                for (int e = 0; e < NE; ++e) if (e != i1 && raw[e] > g2) { g2 = raw[e]; i2 = e; }
                float denom = g1 + g2 + 1e-9f;
                float g1n = g1 / denom, g2n = g2 / denom;
                bool flag = probs[tok] < (g2n / 0.2f);
                idx1a[tok] = i1;
                idx2a[tok] = flag ? i2 : -1;
                g1a[tok] = g1n;
                g2a[tok] = g2n;
                out[tok] = c0v;
            }
        }
        return;
    }
    bid -= 512;
    if (bid < 256) {                                    // ======== We1 -> We1B, 2 units ========
        #pragma unroll
        for (int q2 = 0; q2 < 2; ++q2) {
            const int unit = bid * 2 + q2;              // 0..511
            const int e = unit >> 5, rem = unit & 31;
            const int dblk = rem >> 2, hq = rem & 3;
            const float* src = We1 + (size_t)e * ND * NH + (size_t)(dblk * 64) * NH + hq * 256 + tid;
            unsigned short* dst = We1B + ((size_t)(e * 8 + dblk) * NH + hq * 256 + tid) * 64;
            float v[64];
            #pragma unroll
            for (int j = 0; j < 64; ++j) v[j] = src[(size_t)j * NH];
            #pragma unroll
            for (int q = 0; q < 8; ++q) {
                u16x8 o;
                #pragma unroll
                for (int j = 0; j < 8; ++j) o[j] = f2bf(v[q * 8 + j]);
                *(u16x8*)(dst + q * 8) = o;
            }
        }
        return;
    }
    bid -= 256;
    {                                                   // ======== u: 64 rows/block ========
        float* vvs = wc;                                // alias first 512 floats
        {
            int d = tid * 2;
            float s0 = 0.f, s1 = 0.f;
            #pragma unroll
            for (int j = 0; j < 4; ++j) {
                s0 += W3[d * 4 + j] * W4[j];
                s1 += W3[(d + 1) * 4 + j] * W4[j];
            }
            vvs[d] = s0; vvs[d + 1] = s1;
        }
        __syncthreads();
        const float4* vv4 = (const float4*)vvs;
        const float4 v0 = vv4[l], v1 = vv4[l + 64];
        #pragma unroll
        for (int pass = 0; pass < 2; ++pass) {
            float sums[8];
            #pragma unroll
            for (int i = 0; i < 8; ++i) {
                int gr = bid * 64 + pass * 32 + w * 8 + i;
                const float4* row = (const float4*)(We2 + (size_t)gr * ND);
                float4 a0 = row[l], a1 = row[l + 64];
                sums[i] = a0.x * v0.x + a0.y * v0.y + a0.z * v0.z + a0.w * v0.w
                        + a1.x * v1.x + a1.y * v1.y + a1.z * v1.z + a1.w * v1.w;
            }
            #pragma unroll
            for (int off = 32; off >= 1; off >>= 1)
                #pragma unroll
                for (int i = 0; i < 8; ++i) sums[i] += __shfl_xor(sums[i], off);
            if (l == 0) {
                int gr0 = bid * 64 + pass * 32 + w * 8;
                #pragma unroll
                for (int i = 0; i < 8; ++i) u[gr0 + i] = sums[i];
            }
        }
    }
}

// ---------------- scan (bid<64) + linear1 MFMA (bid in [64,320)) ----------------
__global__ __launch_bounds__(512) void scan_linear1_kernel(const int* __restrict__ idx1a,
                                                           const int* __restrict__ idx2a,
                                                           int* __restrict__ slot_token,
                                                           const unsigned short* __restrict__ Xbf,
                                                           const unsigned short* __restrict__ W1B,
                                                           const float* __restrict__ b1,
                                                           unsigned short* __restrict__ hbf) {
    __shared__ char smem[65536];
    const int tid = threadIdx.x;
    const int w = tid >> 6, l = tid & 63;
    if (blockIdx.x < 64) {                              // ======== scan ========
        const int bb = blockIdx.x;
        const int b = bb >> 4, e = bb & 15;
        int* cnt1 = (int*)smem;
        int* cnt2 = cnt1 + 8;
        int* slot = slot_token + (e * NB + b) * CAP;
        const unsigned long long below = (l == 0) ? 0ull : ((1ull << l) - 1ull);
        const int base0 = w * 256;
        int c1 = 0, c2 = 0;
        #pragma unroll
        for (int it = 0; it < 4; ++it) {
            int n = base0 + it * 64 + l;
            c1 += __popcll(__ballot(idx1a[b * NN + n] == e));
            c2 += __popcll(__ballot(idx2a[b * NN + n] == e));
        }
        if (l == 0) { cnt1[w] = c1; cnt2[w] = c2; }
        __syncthreads();
        int b1c = 0, t1 = 0, b2c = 0, t2 = 0;
        #pragma unroll
        for (int i = 0; i < 8; ++i) {
            int v1 = cnt1[i], v2 = cnt2[i];
            if (i < w) { b1c += v1; b2c += v2; }
            t1 += v1; t2 += v2;
        }
        const int start2 = (t1 < CAP) ? t1 : CAP;
        int c = b1c;
        #pragma unroll
        for (int it = 0; it < 4; ++it) {
            int n = base0 + it * 64 + l;
            bool p = (idx1a[b * NN + n] == e);
            unsigned long long m = __ballot(p);
            int pre = __popcll(m & below);
            if (p) { int pos = c + pre; if (pos < CAP) slot[pos] = n; }
            c += __popcll(m);
        }
        c = start2 + b2c;
        #pragma unroll
        for (int it = 0; it < 4; ++it) {
            int n = base0 + it * 64 + l;
            bool p = (idx2a[b * NN + n] == e);
            unsigned long long m = __ballot(p);
            int pre = __popcll(m & below);
            if (p) { int pos = c + pre; if (pos < CAP) slot[pos] = n | (1 << 30); }
            c += __popcll(m);
        }
        int nfill = start2 + t2; nfill = (nfill < CAP) ? nfill : CAP;
        for (int i = nfill + tid; i < CAP; i += 512) slot[i] = -1;
        return;
    }
    // ======== linear1 ========
    const int lb = blockIdx.x - 64;
    const int m0 = (lb >> 2) * 128, n0 = (lb & 3) * 128;
    const int wm = w >> 1, wn = w & 1;      // 4 x 2 wave grid, wave tile 32x64
    const int lr = l & 15, lk = l >> 4;
    char* Ash0 = smem;                      // 2 x 16384
    char* Bsh0 = smem + 32768;              // 2 x 16384

    auto stage = [&](int Ks, int buf) {
        #pragma unroll
        for (int i = 0; i < 2; ++i) {
            int o = i * 8192 + tid * 16;
            int r = o >> 7, bb = o & 127;
            int sb = bb ^ ((r & 7) << 4);
            gload16((const char*)Xbf + ((size_t)(m0 + r) * ND + Ks * 64) * 2 + sb,
                    Ash0 + buf * 16384 + i * 8192 + w * 1024);
            gload16((const char*)W1B + ((size_t)(Ks * 512 + n0 + r) * 64) * 2 + sb,
                    Bsh0 + buf * 16384 + i * 8192 + w * 1024);
        }
    };

    f32x4 acc[2][4] = {};
    stage(0, 0);
    __syncthreads();
    for (int Ks = 0; Ks < 8; ++Ks) {
        int buf = Ks & 1;
        if (Ks < 7) stage(Ks + 1, buf ^ 1);
        #pragma unroll
        for (int k32 = 0; k32 < 2; ++k32) {
            int kb = (k32 * 32 + 8 * lk) * 2;
            bf16x8 a[2], bfr[4];
            #pragma unroll
            for (int mi = 0; mi < 2; ++mi) {
                int row = wm * 32 + mi * 16 + lr;
                a[mi] = *(const bf16x8*)(Ash0 + buf * 16384 + row * 128 + (kb ^ ((row & 7) << 4)));
            }
            #pragma unroll
            for (int ni = 0; ni < 4; ++ni) {
                int row = wn * 64 + ni * 16 + lr;
                bfr[ni] = *(const bf16x8*)(Bsh0 + buf * 16384 + row * 128 + (kb ^ ((row & 7) << 4)));
            }
            #pragma unroll
            for (int mi = 0; mi < 2; ++mi)
                #pragma unroll
                for (int ni = 0; ni < 4; ++ni)
                    acc[mi][ni] = __builtin_amdgcn_mfma_f32_16x16x32_bf16(a[mi], bfr[ni], acc[mi][ni], 0, 0, 0);
        }
        __syncthreads();
    }
    #pragma unroll
    for (int mi = 0; mi < 2; ++mi)
        #pragma unroll
        for (int ni = 0; ni < 4; ++ni) {
            int col = n0 + wn * 64 + ni * 16 + lr;
            float bb1 = b1[col];
            #pragma unroll
            for (int r = 0; r < 4; ++r) {
                int m = m0 + wm * 32 + mi * 16 + lk * 4 + r;
                hbf[(size_t)m * ND + col] = f2bf(acc[mi][ni][r] + bb1);
            }
        }
}

// ---------------- expert MFMA v2: 64x64 wave tiles, BK=32, atomicAdd epilogue ----------------
__global__ __launch_bounds__(512) void expert_mfma_kernel(const unsigned short* __restrict__ hbf,
                                                          const unsigned short* __restrict__ We1B,
                                                          const float* __restrict__ u,
                                                          const int* __restrict__ slot_token,
                                                          const float* __restrict__ zbuf,
                                                          const float* __restrict__ g1a,
                                                          const float* __restrict__ g2a,
                                                          float* __restrict__ out) {
    __shared__ char Ash[65536];             // 64 slots x 512 k bf16, rows 1024B, XOR (row&7)<<4
    __shared__ char Bsh[2][32768];          // 512 h x 32 k bf16, rows 64B, XOR ((row>>1)&3)<<4
    __shared__ float u_lds[NH];
    __shared__ float sbuf[8][64];
    __shared__ int toks[64];
    const int tid = threadIdx.x;
    const int w = tid >> 6, l = tid & 63;
    const int lr = l & 15, lk = l >> 4;
    // XCD swizzle: all 16 blocks of an expert share an XCD (bid % 8 == e % 8)
    const int bid = blockIdx.x;
    const int e = (bid & 7) | ((bid >> 7) << 3);
    const int chunk = (bid >> 3) & 15;
    const int b = chunk >> 2, c0 = (chunk & 3) * 64;

    if (tid < 64) toks[tid] = slot_token[(e * NB + b) * CAP + c0 + tid];
    u_lds[tid] = u[e * NH + tid];
    u_lds[tid + 512] = u[e * NH + tid + 512];
    __syncthreads();
    // A gather: 64 token rows (full K), wave-uniform row, pre-swizzled source (rule #21)
    #pragma unroll
    for (int i = 0; i < 8; ++i) {
        int r = i * 8 + w;
        int t = toks[r];
        int tok = t & 2047;
        int sb = (l * 16) ^ ((r & 7) << 4);
        const char* src = (t >= 0) ? ((const char*)hbf + ((size_t)(b * NN + tok) * ND) * 2 + sb)
                                   : ((const char*)zbuf + sb);
        gload16(src, Ash + i * 8192 + w * 1024);
    }
    // B stage: (Hc, Ks) = 512 h x 32 k; linear dest, inverse-swizzled source
    auto stageB = [&](int s, int buf) {
        int Hc = s >> 4, Ks = s & 15;
        const size_t base = ((size_t)(e * 8 + (Ks >> 1)) * NH + Hc * 512) * 64 + (Ks & 1) * 32;
        #pragma unroll
        for (int i = 0; i < 4; ++i) {
            int r = i * 128 + w * 16 + (l >> 2);
            int swzr = ((r >> 1) & 3) << 4;
            int ebyte = ((l & 3) * 16) ^ swzr;          // bytes within the 64B row
            gload16((const char*)We1B + (base + (size_t)r * 64) * 2 + ebyte,
                    Bsh[buf] + i * 8192 + w * 1024);
        }
    };
    f32x4 acc[4][4] = {};
    float srow[4][4] = {};
    stageB(0, 0);
    __syncthreads();
    for (int s = 0; s < 32; ++s) {          // 2 Hc x 16 Ks
        int buf = s & 1;
        if (s < 31) stageB(s + 1, buf ^ 1);
        int Ks = s & 15;
        bf16x8 a[4], bb[4];
        #pragma unroll
        for (int mi = 0; mi < 4; ++mi) {
            int row = mi * 16 + lr;
            int kb = (Ks * 64 + lk * 16) ^ ((row & 7) << 4);
            a[mi] = *(const bf16x8*)(Ash + row * 1024 + kb);
        }
        #pragma unroll
        for (int ni = 0; ni < 4; ++ni) {
            int row = w * 64 + ni * 16 + lr;            // h row 0..511
            int kb = (lk * 16) ^ (((row >> 1) & 3) << 4);
            bb[ni] = *(const bf16x8*)(Bsh[buf] + row * 64 + kb);
        }
        #pragma unroll
        for (int mi = 0; mi < 4; ++mi)
            #pragma unroll
            for (int ni = 0; ni < 4; ++ni)
                acc[mi][ni] = __builtin_amdgcn_mfma_f32_16x16x32_bf16(a[mi], bb[ni], acc[mi][ni], 0, 0, 0);
        if ((s & 15) == 15) {               // Hc done: fold lrelu . u, reset acc
            int Hc = s >> 4;
            #pragma unroll
            for (int ni = 0; ni < 4; ++ni) {
                float uu = u_lds[Hc * 512 + w * 64 + ni * 16 + lr];
                #pragma unroll
                for (int mi = 0; mi < 4; ++mi)
                    #pragma unroll
                    for (int r = 0; r < 4; ++r) {
                        float x = acc[mi][ni][r];
                        x = (x > 0.f) ? x : 0.01f * x;
                        srow[mi][r] = fmaf(x, uu, srow[mi][r]);
                        acc[mi][ni][r] = 0.f;
                    }
            }
        }
        __syncthreads();
    }
    // reduce over the 16 col-lanes (lr), stash per-wave partials, then sum 8 waves
    #pragma unroll
    for (int off = 1; off < 16; off <<= 1)
        #pragma unroll
        for (int mi = 0; mi < 4; ++mi)
            #pragma unroll
            for (int r = 0; r < 4; ++r)
                srow[mi][r] += __shfl_xor(srow[mi][r], off);
    if (lr == 0) {
        #pragma unroll
        for (int mi = 0; mi < 4; ++mi)
            #pragma unroll
            for (int r = 0; r < 4; ++r)
                sbuf[w][mi * 16 + lk * 4 + r] = srow[mi][r];
    }
    __syncthreads();
    if (tid < 64) {
        float s = 0.f;
        #pragma unroll
        for (int q = 0; q < 8; ++q) s += sbuf[q][tid];
        int v = toks[tid];
        if (v >= 0) {
            int tok = v & 2047;
            float g = (v & (1 << 30)) ? g2a[b * NN + tok] : g1a[b * NN + tok];
            atomicAdd(out + b * NN + tok, s * g);
        }
    }
}

extern "C" void kernel_launch(void* const* d_in, const int* in_sizes, int n_in,
                              void* d_out, int out_size, void* d_ws, size_t ws_size,
                              hipStream_t stream) {
    const float* X    = (const float*)d_in[0];
    const float* probs= (const float*)d_in[1];
    const float* W1   = (const float*)d_in[2];
    const float* b1   = (const float*)d_in[3];
    const float* Wg   = (const float*)d_in[4];
    const float* We1  = (const float*)d_in[5];
    const float* We2  = (const float*)d_in[6];
    const float* W3   = (const float*)d_in[7];
    const float* b3   = (const float*)d_in[8];
    const float* W4   = (const float*)d_in[9];
    const float* b4   = (const float*)d_in[10];
    float* out = (float*)d_out;

    char* ws = (char*)d_ws;
    size_t off = 0;
    auto alloc = [&](size_t bytes) { void* p = ws + off; off += (bytes + 255) & ~(size_t)255; return p; };
    unsigned short* Xbf  = (unsigned short*)alloc((size_t)NTOK * ND * 2);     // 8 MB
    unsigned short* hbf  = (unsigned short*)alloc((size_t)NTOK * ND * 2);     // 8 MB
    unsigned short* W1B  = (unsigned short*)alloc((size_t)ND * ND * 2);       // 512 KB
    unsigned short* We1B = (unsigned short*)alloc((size_t)NE * NH * ND * 2);  // 16 MB
    float* WcT     = (float*)alloc(NE * ND * 4);
    float* u       = (float*)alloc(NE * NH * 4);
    float* zbuf    = (float*)alloc(1024);
    int*   idx1a   = (int*)alloc(NTOK * 4);
    int*   idx2a   = (int*)alloc(NTOK * 4);
    float* g1a     = (float*)alloc(NTOK * 4);
    float* g2a     = (float*)alloc(NTOK * 4);
    int*   slot_tok= (int*)alloc(NE * NB * CAP * 4);
    (void)ws_size; (void)in_sizes; (void)n_in; (void)out_size;

    prep_w_kernel<<<144, 256, 0, stream>>>(W1, Wg, W1B, WcT, zbuf);
    gating_stream_kernel<<<1024, 256, 0, stream>>>(X, WcT, probs, b3, W4, b4,
                                                   We1, We2, W3,
                                                   Xbf, We1B, u,
                                                   idx1a, idx2a, g1a, g2a, out);
    scan_linear1_kernel<<<320, 512, 0, stream>>>(idx1a, idx2a, slot_tok,
                                                 Xbf, W1B, b1, hbf);
    expert_mfma_kernel<<<256, 512, 0, stream>>>(hbf, We1B, u, slot_tok, zbuf, g1a, g2a, out);
}

// Round 18
// 81.557 us; speedup vs baseline: 2.6108x; 1.0058x over previous
//
#include <hip/hip_runtime.h>
#include <hip/hip_bf16.h>

#define NB 4
#define NN 2048
#define ND 512
#define NE 16
#define NH 1024
#define CAP 256
#define NTOK (NB*NN)

typedef __attribute__((ext_vector_type(8))) short bf16x8;
typedef __attribute__((ext_vector_type(4))) float f32x4;
typedef __attribute__((ext_vector_type(8))) unsigned short u16x8;

__device__ __forceinline__ void gload16(const void* gsrc, void* lds) {
    __builtin_amdgcn_global_load_lds((const __attribute__((address_space(1))) void*)gsrc,
                                     (__attribute__((address_space(3))) void*)lds, 16, 0, 0);
}
__device__ __forceinline__ unsigned short f2bf(float f) {
    union { __hip_bfloat16 b; unsigned short u; } v; v.b = __float2bfloat16(f); return v.u;
}

// ------- kernel A (tiny critical prefix): WcT + W1B + zbuf -------
__global__ __launch_bounds__(256) void prep_w_kernel(const float* __restrict__ W1,
                                                     const float* __restrict__ Wg,
                                                     unsigned short* __restrict__ W1B,
                                                     float* __restrict__ WcT,
                                                     float* __restrict__ zbuf) {
    const int tid = threadIdx.x;
    int bid = blockIdx.x;
    if (bid < 128) {                                    // ---- WcT: wave-per-d
        if (bid == 0) zbuf[tid] = 0.f;
        const int w = tid >> 6, l = tid & 63;
        const int d = bid * 4 + w;
        float a0 = 0.f, a1 = 0.f, a2 = 0.f, a3 = 0.f, a4 = 0.f, a5 = 0.f, a6 = 0.f, a7 = 0.f;
        float a8 = 0.f, a9 = 0.f, aA = 0.f, aB = 0.f, aC = 0.f, aD = 0.f, aE = 0.f, aF = 0.f;
        #pragma unroll
        for (int ch = 0; ch < 8; ++ch) {
            float x = W1[(size_t)d * ND + ch * 64 + l];
            const float4* wg4 = (const float4*)(Wg + (size_t)(ch * 64 + l) * NE);
            float4 g0 = wg4[0], g1 = wg4[1], g2 = wg4[2], g3 = wg4[3];
            a0 = fmaf(x, g0.x, a0); a1 = fmaf(x, g0.y, a1); a2 = fmaf(x, g0.z, a2); a3 = fmaf(x, g0.w, a3);
            a4 = fmaf(x, g1.x, a4); a5 = fmaf(x, g1.y, a5); a6 = fmaf(x, g1.z, a6); a7 = fmaf(x, g1.w, a7);
            a8 = fmaf(x, g2.x, a8); a9 = fmaf(x, g2.y, a9); aA = fmaf(x, g2.z, aA); aB = fmaf(x, g2.w, aB);
            aC = fmaf(x, g3.x, aC); aD = fmaf(x, g3.y, aD); aE = fmaf(x, g3.z, aE); aF = fmaf(x, g3.w, aF);
        }
        float accs[16] = {a0, a1, a2, a3, a4, a5, a6, a7, a8, a9, aA, aB, aC, aD, aE, aF};
        #pragma unroll
        for (int off = 32; off >= 1; off >>= 1)
            #pragma unroll
            for (int e = 0; e < 16; ++e) accs[e] += __shfl_xor(accs[e], off);
        #pragma unroll
        for (int e = 0; e < 16; ++e)
            if (l == e) WcT[e * ND + d] = accs[e];
        return;
    }
    bid -= 128;
    {                                                   // ---- W1B transpose, 64 d/thread
        int dblk = bid >> 1, hblk = bid & 1;
        const float* src = W1 + (size_t)(dblk * 64) * ND + hblk * 256 + tid;
        unsigned short* dst = W1B + (size_t)(dblk * 512 + hblk * 256 + tid) * 64;
        float v[64];
        #pragma unroll
        for (int j = 0; j < 64; ++j) v[j] = src[(size_t)j * ND];
        #pragma unroll
        for (int q = 0; q < 8; ++q) {
            u16x8 o;
            #pragma unroll
            for (int j = 0; j < 8; ++j) o[j] = f2bf(v[q * 8 + j]);
            *(u16x8*)(dst + q * 8) = o;
        }
    }
}

// ------- kernel B: gating (512) + interleaved We1^T (512) / u (512) stream blocks -------
__global__ __launch_bounds__(256) void gating_stream_kernel(const float* __restrict__ X,
                                                            const float* __restrict__ WcT,
                                                            const float* __restrict__ probs,
                                                            const float* __restrict__ b3,
                                                            const float* __restrict__ W4,
                                                            const float* __restrict__ b4,
                                                            const float* __restrict__ We1,
                                                            const float* __restrict__ We2,
                                                            const float* __restrict__ W3,
                                                            unsigned short* __restrict__ Xbf,
                                                            unsigned short* __restrict__ We1B,
                                                            float* __restrict__ u,
                                                            int* __restrict__ idx1a, int* __restrict__ idx2a,
                                                            float* __restrict__ g1a, float* __restrict__ g2a,
                                                            float* __restrict__ out) {
    __shared__ float wc[NE * ND];           // 32KB (u section aliases wc[0..511])
    const int tid = threadIdx.x;
    int bid = blockIdx.x;
    const int w = tid >> 6, l = tid & 63;
    if (bid < 512) {                                    // ======== gating ========
        #pragma unroll
        for (int i = 0; i < 32; ++i) wc[tid + 256 * i] = WcT[tid + 256 * i];
        float c0v = b4[0];
        #pragma unroll
        for (int j = 0; j < 4; ++j) c0v += b3[j] * W4[j];
        __syncthreads();
        const float4* wc4 = (const float4*)wc;
        for (int j = 0; j < 4; ++j) {
            int tok = bid * 16 + j * 4 + w;
            const float4* xrow = (const float4*)(X + (size_t)tok * ND);
            float4 x0 = xrow[l], x1 = xrow[l + 64];
            {   // side output: bf16 X
                ushort4 o0, o1;
                o0.x = f2bf(x0.x); o0.y = f2bf(x0.y); o0.z = f2bf(x0.z); o0.w = f2bf(x0.w);
                o1.x = f2bf(x1.x); o1.y = f2bf(x1.y); o1.z = f2bf(x1.z); o1.w = f2bf(x1.w);
                *(ushort4*)(Xbf + (size_t)tok * ND + 4 * l) = o0;
                *(ushort4*)(Xbf + (size_t)tok * ND + 256 + 4 * l) = o1;
            }
            float acc[NE];
            #pragma unroll
            for (int e = 0; e < NE; ++e) {
                float4 w0 = wc4[e * 128 + l], w1 = wc4[e * 128 + l + 64];
                acc[e] = x0.x * w0.x + x0.y * w0.y + x0.z * w0.z + x0.w * w0.w
                       + x1.x * w1.x + x1.y * w1.y + x1.z * w1.z + x1.w * w1.w;
            }
            #pragma unroll
            for (int off = 32; off >= 1; off >>= 1)
                #pragma unroll
                for (int e = 0; e < NE; ++e) acc[e] += __shfl_xor(acc[e], off);

            if (l == 0) {
                float m = acc[0];
                #pragma unroll
                for (int e = 1; e < NE; ++e) m = fmaxf(m, acc[e]);
                float raw[NE]; float s = 0.f;
                #pragma unroll
                for (int e = 0; e < NE; ++e) { raw[e] = expf(acc[e] - m); s += raw[e]; }
                #pragma unroll
                for (int e = 0; e < NE; ++e) raw[e] = raw[e] / s;
                int i1 = 0; float g1 = raw[0];
                #pragma unroll
                for (int e = 1; e < NE; ++e) if (raw[e] > g1) { g1 = raw[e]; i1 = e; }
                int i2 = -1; float g2 = -1.f;
                #pragma unroll
                for (int e = 0; e < NE; ++e) if (e != i1 && raw[e] > g2) { g2 = raw[e]; i2 = e; }
                float denom = g1 + g2 + 1e-9f;
                float g1n = g1 / denom, g2n = g2 / denom;
                bool flag = probs[tok] < (g2n / 0.2f);
                idx1a[tok] = i1;
                idx2a[tok] = flag ? i2 : -1;
                g1a[tok] = g1n;
                g2a[tok] = g2n;
                out[tok] = c0v;
            }
        }
        return;
    }
    const int sb = bid - 512;                           // 0..1023 stream blocks, interleaved
    if (sb & 1) {                                       // ======== We1 -> We1B (1 unit) ========
        const int unit = sb >> 1;                       // 0..511
        const int e = unit >> 5, rem = unit & 31;
        const int dblk = rem >> 2, hq = rem & 3;
        const float* src = We1 + (size_t)e * ND * NH + (size_t)(dblk * 64) * NH + hq * 256 + tid;
        unsigned short* dst = We1B + ((size_t)(e * 8 + dblk) * NH + hq * 256 + tid) * 64;
        float v[64];
        #pragma unroll
        for (int j = 0; j < 64; ++j) v[j] = src[(size_t)j * NH];
        #pragma unroll
        for (int q = 0; q < 8; ++q) {
            u16x8 o;
            #pragma unroll
            for (int j = 0; j < 8; ++j) o[j] = f2bf(v[q * 8 + j]);
            *(u16x8*)(dst + q * 8) = o;
        }
        return;
    }
    {                                                   // ======== u: 32 rows/block ========
        const int ub = sb >> 1;                         // 0..511
        float* vvs = wc;                                // alias first 512 floats
        {
            int d = tid * 2;
            float s0 = 0.f, s1 = 0.f;
            #pragma unroll
            for (int j = 0; j < 4; ++j) {
                s0 += W3[d * 4 + j] * W4[j];
                s1 += W3[(d + 1) * 4 + j] * W4[j];
            }
            vvs[d] = s0; vvs[d + 1] = s1;
        }
        __syncthreads();
        const float4* vv4 = (const float4*)vvs;
        const float4 v0 = vv4[l], v1 = vv4[l + 64];
        float sums[8];
        #pragma unroll
        for (int i = 0; i < 8; ++i) {
            int gr = ub * 32 + w * 8 + i;
            const float4* row = (const float4*)(We2 + (size_t)gr * ND);
            float4 a0 = row[l], a1 = row[l + 64];
            sums[i] = a0.x * v0.x + a0.y * v0.y + a0.z * v0.z + a0.w * v0.w
                    + a1.x * v1.x + a1.y * v1.y + a1.z * v1.z + a1.w * v1.w;
        }
        #pragma unroll
        for (int off = 32; off >= 1; off >>= 1)
            #pragma unroll
            for (int i = 0; i < 8; ++i) sums[i] += __shfl_xor(sums[i], off);
        if (l == 0) {
            int gr0 = ub * 32 + w * 8;
            #pragma unroll
            for (int i = 0; i < 8; ++i) u[gr0 + i] = sums[i];
        }
    }
}

// ---------------- scan (bid<64) + linear1 MFMA (bid in [64,320)) ----------------
__global__ __launch_bounds__(512) void scan_linear1_kernel(const int* __restrict__ idx1a,
                                                           const int* __restrict__ idx2a,
                                                           int* __restrict__ slot_token,
                                                           const unsigned short* __restrict__ Xbf,
                                                           const unsigned short* __restrict__ W1B,
                                                           const float* __restrict__ b1,
                                                           unsigned short* __restrict__ hbf) {
    __shared__ char smem[65536];
    const int tid = threadIdx.x;
    const int w = tid >> 6, l = tid & 63;
    if (blockIdx.x < 64) {                              // ======== scan ========
        const int bb = blockIdx.x;
        const int b = bb >> 4, e = bb & 15;
        int* cnt1 = (int*)smem;
        int* cnt2 = cnt1 + 8;
        int* slot = slot_token + (e * NB + b) * CAP;
        const unsigned long long below = (l == 0) ? 0ull : ((1ull << l) - 1ull);
        const int base0 = w * 256;
        int c1 = 0, c2 = 0;
        #pragma unroll
        for (int it = 0; it < 4; ++it) {
            int n = base0 + it * 64 + l;
            c1 += __popcll(__ballot(idx1a[b * NN + n] == e));
            c2 += __popcll(__ballot(idx2a[b * NN + n] == e));
        }
        if (l == 0) { cnt1[w] = c1; cnt2[w] = c2; }
        __syncthreads();
        int b1c = 0, t1 = 0, b2c = 0, t2 = 0;
        #pragma unroll
        for (int i = 0; i < 8; ++i) {
            int v1 = cnt1[i], v2 = cnt2[i];
            if (i < w) { b1c += v1; b2c += v2; }
            t1 += v1; t2 += v2;
        }
        const int start2 = (t1 < CAP) ? t1 : CAP;
        int c = b1c;
        #pragma unroll
        for (int it = 0; it < 4; ++it) {
            int n = base0 + it * 64 + l;
            bool p = (idx1a[b * NN + n] == e);
            unsigned long long m = __ballot(p);
            int pre = __popcll(m & below);
            if (p) { int pos = c + pre; if (pos < CAP) slot[pos] = n; }
            c += __popcll(m);
        }
        c = start2 + b2c;
        #pragma unroll
        for (int it = 0; it < 4; ++it) {
            int n = base0 + it * 64 + l;
            bool p = (idx2a[b * NN + n] == e);
            unsigned long long m = __ballot(p);
            int pre = __popcll(m & below);
            if (p) { int pos = c + pre; if (pos < CAP) slot[pos] = n | (1 << 30); }
            c += __popcll(m);
        }
        int nfill = start2 + t2; nfill = (nfill < CAP) ? nfill : CAP;
        for (int i = nfill + tid; i < CAP; i += 512) slot[i] = -1;
        return;
    }
    // ======== linear1 ========
    const int lb = blockIdx.x - 64;
    const int m0 = (lb >> 2) * 128, n0 = (lb & 3) * 128;
    const int wm = w >> 1, wn = w & 1;      // 4 x 2 wave grid, wave tile 32x64
    const int lr = l & 15, lk = l >> 4;
    char* Ash0 = smem;                      // 2 x 16384
    char* Bsh0 = smem + 32768;              // 2 x 16384

    auto stage = [&](int Ks, int buf) {
        #pragma unroll
        for (int i = 0; i < 2; ++i) {
            int o = i * 8192 + tid * 16;
            int r = o >> 7, bb = o & 127;
            int sb2 = bb ^ ((r & 7) << 4);
            gload16((const char*)Xbf + ((size_t)(m0 + r) * ND + Ks * 64) * 2 + sb2,
                    Ash0 + buf * 16384 + i * 8192 + w * 1024);
            gload16((const char*)W1B + ((size_t)(Ks * 512 + n0 + r) * 64) * 2 + sb2,
                    Bsh0 + buf * 16384 + i * 8192 + w * 1024);
        }
    };

    f32x4 acc[2][4] = {};
    stage(0, 0);
    __syncthreads();
    for (int Ks = 0; Ks < 8; ++Ks) {
        int buf = Ks & 1;
        if (Ks < 7) stage(Ks + 1, buf ^ 1);
        #pragma unroll
        for (int k32 = 0; k32 < 2; ++k32) {
            int kb = (k32 * 32 + 8 * lk) * 2;
            bf16x8 a[2], bfr[4];
            #pragma unroll
            for (int mi = 0; mi < 2; ++mi) {
                int row = wm * 32 + mi * 16 + lr;
                a[mi] = *(const bf16x8*)(Ash0 + buf * 16384 + row * 128 + (kb ^ ((row & 7) << 4)));
            }
            #pragma unroll
            for (int ni = 0; ni < 4; ++ni) {
                int row = wn * 64 + ni * 16 + lr;
                bfr[ni] = *(const bf16x8*)(Bsh0 + buf * 16384 + row * 128 + (kb ^ ((row & 7) << 4)));
            }
            #pragma unroll
            for (int mi = 0; mi < 2; ++mi)
                #pragma unroll
                for (int ni = 0; ni < 4; ++ni)
                    acc[mi][ni] = __builtin_amdgcn_mfma_f32_16x16x32_bf16(a[mi], bfr[ni], acc[mi][ni], 0, 0, 0);
        }
        __syncthreads();
    }
    #pragma unroll
    for (int mi = 0; mi < 2; ++mi)
        #pragma unroll
        for (int ni = 0; ni < 4; ++ni) {
            int col = n0 + wn * 64 + ni * 16 + lr;
            float bb1 = b1[col];
            #pragma unroll
            for (int r = 0; r < 4; ++r) {
                int m = m0 + wm * 32 + mi * 16 + lk * 4 + r;
                hbf[(size_t)m * ND + col] = f2bf(acc[mi][ni][r] + bb1);
            }
        }
}

// ---------------- expert MFMA v2: 64x64 wave tiles, BK=32, atomicAdd epilogue ----------------
__global__ __launch_bounds__(512) void expert_mfma_kernel(const unsigned short* __restrict__ hbf,
                                                          const unsigned short* __restrict__ We1B,
                                                          const float* __restrict__ u,
                                                          const int* __restrict__ slot_token,
                                                          const float* __restrict__ zbuf,
                                                          const float* __restrict__ g1a,
                                                          const float* __restrict__ g2a,
                                                          float* __restrict__ out) {
    __shared__ char Ash[65536];             // 64 slots x 512 k bf16, rows 1024B, XOR (row&7)<<4
    __shared__ char Bsh[2][32768];          // 512 h x 32 k bf16, rows 64B, XOR ((row>>1)&3)<<4
    __shared__ float u_lds[NH];
    __shared__ float sbuf[8][64];
    __shared__ int toks[64];
    const int tid = threadIdx.x;
    const int w = tid >> 6, l = tid & 63;
    const int lr = l & 15, lk = l >> 4;
    // XCD swizzle: all 16 blocks of an expert share an XCD (bid % 8 == e % 8)
    const int bid = blockIdx.x;
    const int e = (bid & 7) | ((bid >> 7) << 3);
    const int chunk = (bid >> 3) & 15;
    const int b = chunk >> 2, c0 = (chunk & 3) * 64;

    if (tid < 64) toks[tid] = slot_token[(e * NB + b) * CAP + c0 + tid];
    u_lds[tid] = u[e * NH + tid];
    u_lds[tid + 512] = u[e * NH + tid + 512];
    __syncthreads();
    // A gather: 64 token rows (full K), wave-uniform row, pre-swizzled source (rule #21)
    #pragma unroll
    for (int i = 0; i < 8; ++i) {
        int r = i * 8 + w;
        int t = toks[r];
        int tok = t & 2047;
        int sb = (l * 16) ^ ((r & 7) << 4);
        const char* src = (t >= 0) ? ((const char*)hbf + ((size_t)(b * NN + tok) * ND) * 2 + sb)
                                   : ((const char*)zbuf + sb);
        gload16(src, Ash + i * 8192 + w * 1024);
    }
    // B stage: (Hc, Ks) = 512 h x 32 k; linear dest, inverse-swizzled source
    auto stageB = [&](int s, int buf) {
        int Hc = s >> 4, Ks = s & 15;
        const size_t base = ((size_t)(e * 8 + (Ks >> 1)) * NH + Hc * 512) * 64 + (Ks & 1) * 32;
        #pragma unroll
        for (int i = 0; i < 4; ++i) {
            int r = i * 128 + w * 16 + (l >> 2);
            int swzr = ((r >> 1) & 3) << 4;
            int ebyte = ((l & 3) * 16) ^ swzr;          // bytes within the 64B row
            gload16((const char*)We1B + (base + (size_t)r * 64) * 2 + ebyte,
                    Bsh[buf] + i * 8192 + w * 1024);
        }
    };
    f32x4 acc[4][4] = {};
    float srow[4][4] = {};
    stageB(0, 0);
    __syncthreads();
    for (int s = 0; s < 32; ++s) {          // 2 Hc x 16 Ks
        int buf = s & 1;
        if (s < 31) stageB(s + 1, buf ^ 1);
        int Ks = s & 15;
        bf16x8 a[4], bb[4];
        #pragma unroll
        for (int mi = 0; mi < 4; ++mi) {
            int row = mi * 16 + lr;
            int kb = (Ks * 64 + lk * 16) ^ ((row & 7) << 4);
            a[mi] = *(const bf16x8*)(Ash + row * 1024 + kb);
        }
        #pragma unroll
        for (int ni = 0; ni < 4; ++ni) {
            int row = w * 64 + ni * 16 + lr;            // h row 0..511
            int kb = (lk * 16) ^ (((row >> 1) & 3) << 4);
            bb[ni] = *(const bf16x8*)(Bsh[buf] + row * 64 + kb);
        }
        #pragma unroll
        for (int mi = 0; mi < 4; ++mi)
            #pragma unroll
            for (int ni = 0; ni < 4; ++ni)
                acc[mi][ni] = __builtin_amdgcn_mfma_f32_16x16x32_bf16(a[mi], bb[ni], acc[mi][ni], 0, 0, 0);
        if ((s & 15) == 15) {               // Hc done: fold lrelu . u, reset acc
            int Hc = s >> 4;
            #pragma unroll
            for (int ni = 0; ni < 4; ++ni) {
                float uu = u_lds[Hc * 512 + w * 64 + ni * 16 + lr];
                #pragma unroll
                for (int mi = 0; mi < 4; ++mi)
                    #pragma unroll
                    for (int r = 0; r < 4; ++r) {
                        float x = acc[mi][ni][r];
                        x = (x > 0.f) ? x : 0.01f * x;
                        srow[mi][r] = fmaf(x, uu, srow[mi][r]);
                        acc[mi][ni][r] = 0.f;
                    }
            }
        }
        __syncthreads();
    }
    // reduce over the 16 col-lanes (lr), stash per-wave partials, then sum 8 waves
    #pragma unroll
    for (int off = 1; off < 16; off <<= 1)
        #pragma unroll
        for (int mi = 0; mi < 4; ++mi)
            #pragma unroll
            for (int r = 0; r < 4; ++r)
                srow[mi][r] += __shfl_xor(srow[mi][r], off);
    if (lr == 0) {
        #pragma unroll
        for (int mi = 0; mi < 4; ++mi)
            #pragma unroll
            for (int r = 0; r < 4; ++r)
                sbuf[w][mi * 16 + lk * 4 + r] = srow[mi][r];
    }
    __syncthreads();
    if (tid < 64) {
        float s = 0.f;
        #pragma unroll
        for (int q = 0; q < 8; ++q) s += sbuf[q][tid];
        int v = toks[tid];
        if (v >= 0) {
            int tok = v & 2047;
            float g = (v & (1 << 30)) ? g2a[b * NN + tok] : g1a[b * NN + tok];
            atomicAdd(out + b * NN + tok, s * g);
        }
    }
}

extern "C" void kernel_launch(void* const* d_in, const int* in_sizes, int n_in,
                              void* d_out, int out_size, void* d_ws, size_t ws_size,
                              hipStream_t stream) {
    const float* X    = (const float*)d_in[0];
    const float* probs= (const float*)d_in[1];
    const float* W1   = (const float*)d_in[2];
    const float* b1   = (const float*)d_in[3];
    const float* Wg   = (const float*)d_in[4];
    const float* We1  = (const float*)d_in[5];
    const float* We2  = (const float*)d_in[6];
    const float* W3   = (const float*)d_in[7];
    const float* b3   = (const float*)d_in[8];
    const float* W4   = (const float*)d_in[9];
    const float* b4   = (const float*)d_in[10];
    float* out = (float*)d_out;

    char* ws = (char*)d_ws;
    size_t off = 0;
    auto alloc = [&](size_t bytes) { void* p = ws + off; off += (bytes + 255) & ~(size_t)255; return p; };
    unsigned short* Xbf  = (unsigned short*)alloc((size_t)NTOK * ND * 2);     // 8 MB
    unsigned short* hbf  = (unsigned short*)alloc((size_t)NTOK * ND * 2);     // 8 MB
    unsigned short* W1B  = (unsigned short*)alloc((size_t)ND * ND * 2);       // 512 KB
    unsigned short* We1B = (unsigned short*)alloc((size_t)NE * NH * ND * 2);  // 16 MB
    float* WcT     = (float*)alloc(NE * ND * 4);
    float* u       = (float*)alloc(NE * NH * 4);
    float* zbuf    = (float*)alloc(1024);
    int*   idx1a   = (int*)alloc(NTOK * 4);
    int*   idx2a   = (int*)alloc(NTOK * 4);
    float* g1a     = (float*)alloc(NTOK * 4);
    float* g2a     = (float*)alloc(NTOK * 4);
    int*   slot_tok= (int*)alloc(NE * NB * CAP * 4);
    (void)ws_size; (void)in_sizes; (void)n_in; (void)out_size;

    prep_w_kernel<<<144, 256, 0, stream>>>(W1, Wg, W1B, WcT, zbuf);
    gating_stream_kernel<<<1536, 256, 0, stream>>>(X, WcT, probs, b3, W4, b4,
                                                   We1, We2, W3,
                                                   Xbf, We1B, u,
                                                   idx1a, idx2a, g1a, g2a, out);
    scan_linear1_kernel<<<320, 512, 0, stream>>>(idx1a, idx2a, slot_tok,
                                                 Xbf, W1B, b1, hbf);
    expert_mfma_kernel<<<256, 512, 0, stream>>>(hbf, We1B, u, slot_tok, zbuf, g1a, g2a, out);
}

// Round 19
// 79.976 us; speedup vs baseline: 2.6625x; 1.0198x over previous
//
#include <hip/hip_runtime.h>
#include <hip/hip_bf16.h>

#define NB 4
#define NN 2048
#define ND 512
#define NE 16
#define NH 1024
#define CAP 256
#define NTOK (NB*NN)

typedef __attribute__((ext_vector_type(8))) short bf16x8;
typedef __attribute__((ext_vector_type(4))) float f32x4;
typedef __attribute__((ext_vector_type(8))) unsigned short u16x8;

__device__ __forceinline__ void gload16(const void* gsrc, void* lds) {
    __builtin_amdgcn_global_load_lds((const __attribute__((address_space(1))) void*)gsrc,
                                     (__attribute__((address_space(3))) void*)lds, 16, 0, 0);
}
__device__ __forceinline__ unsigned short f2bf(float f) {
    union { __hip_bfloat16 b; unsigned short u; } v; v.b = __float2bfloat16(f); return v.u;
}

// ------- kernel A (tiny critical prefix): WcT + W1B + zbuf -------
__global__ __launch_bounds__(256) void prep_w_kernel(const float* __restrict__ W1,
                                                     const float* __restrict__ Wg,
                                                     unsigned short* __restrict__ W1B,
                                                     float* __restrict__ WcT,
                                                     float* __restrict__ zbuf) {
    const int tid = threadIdx.x;
    int bid = blockIdx.x;
    if (bid < 128) {                                    // ---- WcT: wave-per-d
        if (bid == 0) zbuf[tid] = 0.f;
        const int w = tid >> 6, l = tid & 63;
        const int d = bid * 4 + w;
        float a0 = 0.f, a1 = 0.f, a2 = 0.f, a3 = 0.f, a4 = 0.f, a5 = 0.f, a6 = 0.f, a7 = 0.f;
        float a8 = 0.f, a9 = 0.f, aA = 0.f, aB = 0.f, aC = 0.f, aD = 0.f, aE = 0.f, aF = 0.f;
        #pragma unroll
        for (int ch = 0; ch < 8; ++ch) {
            float x = W1[(size_t)d * ND + ch * 64 + l];
            const float4* wg4 = (const float4*)(Wg + (size_t)(ch * 64 + l) * NE);
            float4 g0 = wg4[0], g1 = wg4[1], g2 = wg4[2], g3 = wg4[3];
            a0 = fmaf(x, g0.x, a0); a1 = fmaf(x, g0.y, a1); a2 = fmaf(x, g0.z, a2); a3 = fmaf(x, g0.w, a3);
            a4 = fmaf(x, g1.x, a4); a5 = fmaf(x, g1.y, a5); a6 = fmaf(x, g1.z, a6); a7 = fmaf(x, g1.w, a7);
            a8 = fmaf(x, g2.x, a8); a9 = fmaf(x, g2.y, a9); aA = fmaf(x, g2.z, aA); aB = fmaf(x, g2.w, aB);
            aC = fmaf(x, g3.x, aC); aD = fmaf(x, g3.y, aD); aE = fmaf(x, g3.z, aE); aF = fmaf(x, g3.w, aF);
        }
        float accs[16] = {a0, a1, a2, a3, a4, a5, a6, a7, a8, a9, aA, aB, aC, aD, aE, aF};
        #pragma unroll
        for (int off = 32; off >= 1; off >>= 1)
            #pragma unroll
            for (int e = 0; e < 16; ++e) accs[e] += __shfl_xor(accs[e], off);
        #pragma unroll
        for (int e = 0; e < 16; ++e)
            if (l == e) WcT[e * ND + d] = accs[e];
        return;
    }
    bid -= 128;
    {                                                   // ---- W1B transpose, 64 d/thread
        int dblk = bid >> 1, hblk = bid & 1;
        const float* src = W1 + (size_t)(dblk * 64) * ND + hblk * 256 + tid;
        unsigned short* dst = W1B + (size_t)(dblk * 512 + hblk * 256 + tid) * 64;
        float v[64];
        #pragma unroll
        for (int j = 0; j < 64; ++j) v[j] = src[(size_t)j * ND];
        #pragma unroll
        for (int q = 0; q < 8; ++q) {
            u16x8 o;
            #pragma unroll
            for (int j = 0; j < 8; ++j) o[j] = f2bf(v[q * 8 + j]);
            *(u16x8*)(dst + q * 8) = o;
        }
    }
}

// ------- kernel B: gating (512) + interleaved We1^T (512) / u (512); 64-VGPR class -------
__global__ __launch_bounds__(256, 8) void gating_stream_kernel(const float* __restrict__ X,
                                                               const float* __restrict__ WcT,
                                                               const float* __restrict__ probs,
                                                               const float* __restrict__ b3,
                                                               const float* __restrict__ W4,
                                                               const float* __restrict__ b4,
                                                               const float* __restrict__ We1,
                                                               const float* __restrict__ We2,
                                                               const float* __restrict__ W3,
                                                               unsigned short* __restrict__ Xbf,
                                                               unsigned short* __restrict__ We1B,
                                                               float* __restrict__ u,
                                                               int* __restrict__ idx1a, int* __restrict__ idx2a,
                                                               float* __restrict__ g1a, float* __restrict__ g2a,
                                                               float* __restrict__ out) {
    __shared__ float wc[NE * ND];           // 32KB (u section aliases wc[0..511])
    const int tid = threadIdx.x;
    int bid = blockIdx.x;
    const int w = tid >> 6, l = tid & 63;
    if (bid < 512) {                                    // ======== gating ========
        #pragma unroll
        for (int i = 0; i < 32; ++i) wc[tid + 256 * i] = WcT[tid + 256 * i];
        float c0v = b4[0];
        #pragma unroll
        for (int j = 0; j < 4; ++j) c0v += b3[j] * W4[j];
        __syncthreads();
        const float4* wc4 = (const float4*)wc;
        for (int j = 0; j < 4; ++j) {
            int tok = bid * 16 + j * 4 + w;
            const float4* xrow = (const float4*)(X + (size_t)tok * ND);
            float4 x0 = xrow[l], x1 = xrow[l + 64];
            {   // side output: bf16 X
                ushort4 o0, o1;
                o0.x = f2bf(x0.x); o0.y = f2bf(x0.y); o0.z = f2bf(x0.z); o0.w = f2bf(x0.w);
                o1.x = f2bf(x1.x); o1.y = f2bf(x1.y); o1.z = f2bf(x1.z); o1.w = f2bf(x1.w);
                *(ushort4*)(Xbf + (size_t)tok * ND + 4 * l) = o0;
                *(ushort4*)(Xbf + (size_t)tok * ND + 256 + 4 * l) = o1;
            }
            float acc[NE];
            #pragma unroll
            for (int e = 0; e < NE; ++e) {
                float4 w0 = wc4[e * 128 + l], w1 = wc4[e * 128 + l + 64];
                acc[e] = x0.x * w0.x + x0.y * w0.y + x0.z * w0.z + x0.w * w0.w
                       + x1.x * w1.x + x1.y * w1.y + x1.z * w1.z + x1.w * w1.w;
            }
            #pragma unroll
            for (int off = 32; off >= 1; off >>= 1)
                #pragma unroll
                for (int e = 0; e < NE; ++e) acc[e] += __shfl_xor(acc[e], off);

            if (l == 0) {
                float m = acc[0];
                #pragma unroll
                for (int e = 1; e < NE; ++e) m = fmaxf(m, acc[e]);
                float s = 0.f;
                #pragma unroll
                for (int e = 0; e < NE; ++e) { acc[e] = expf(acc[e] - m); s += acc[e]; }
                float inv = 1.f / s;
                #pragma unroll
                for (int e = 0; e < NE; ++e) acc[e] *= inv;
                int i1 = 0; float g1 = acc[0];
                #pragma unroll
                for (int e = 1; e < NE; ++e) if (acc[e] > g1) { g1 = acc[e]; i1 = e; }
                int i2 = -1; float g2 = -1.f;
                #pragma unroll
                for (int e = 0; e < NE; ++e) if (e != i1 && acc[e] > g2) { g2 = acc[e]; i2 = e; }
                float denom = g1 + g2 + 1e-9f;
                float g1n = g1 / denom, g2n = g2 / denom;
                bool flag = probs[tok] < (g2n / 0.2f);
                idx1a[tok] = i1;
                idx2a[tok] = flag ? i2 : -1;
                g1a[tok] = g1n;
                g2a[tok] = g2n;
                out[tok] = c0v;
            }
        }
        return;
    }
    const int sb = bid - 512;                           // 0..1023 stream blocks, interleaved
    if (sb & 1) {                                       // ======== We1 -> We1B, 2 halves of 32 ========
        const int unit = sb >> 1;                       // 0..511
        const int e = unit >> 5, rem = unit & 31;
        const int dblk = rem >> 2, hq = rem & 3;
        const float* src = We1 + (size_t)e * ND * NH + (size_t)(dblk * 64) * NH + hq * 256 + tid;
        unsigned short* dst = We1B + ((size_t)(e * 8 + dblk) * NH + hq * 256 + tid) * 64;
        #pragma unroll
        for (int half = 0; half < 2; ++half) {
            float v[32];
            #pragma unroll
            for (int j = 0; j < 32; ++j) v[j] = src[(size_t)(half * 32 + j) * NH];
            #pragma unroll
            for (int q = 0; q < 4; ++q) {
                u16x8 o;
                #pragma unroll
                for (int j = 0; j < 8; ++j) o[j] = f2bf(v[q * 8 + j]);
                *(u16x8*)(dst + half * 32 + q * 8) = o;
            }
        }
        return;
    }
    {                                                   // ======== u: 32 rows/block ========
        const int ub = sb >> 1;                         // 0..511
        float* vvs = wc;                                // alias first 512 floats
        {
            int d = tid * 2;
            float s0 = 0.f, s1 = 0.f;
            #pragma unroll
            for (int j = 0; j < 4; ++j) {
                s0 += W3[d * 4 + j] * W4[j];
                s1 += W3[(d + 1) * 4 + j] * W4[j];
            }
            vvs[d] = s0; vvs[d + 1] = s1;
        }
        __syncthreads();
        const float4* vv4 = (const float4*)vvs;
        const float4 v0 = vv4[l], v1 = vv4[l + 64];
        float sums[8];
        #pragma unroll
        for (int i = 0; i < 8; ++i) {
            int gr = ub * 32 + w * 8 + i;
            const float4* row = (const float4*)(We2 + (size_t)gr * ND);
            float4 a0 = row[l], a1 = row[l + 64];
            sums[i] = a0.x * v0.x + a0.y * v0.y + a0.z * v0.z + a0.w * v0.w
                    + a1.x * v1.x + a1.y * v1.y + a1.z * v1.z + a1.w * v1.w;
        }
        #pragma unroll
        for (int off = 32; off >= 1; off >>= 1)
            #pragma unroll
            for (int i = 0; i < 8; ++i) sums[i] += __shfl_xor(sums[i], off);
        if (l == 0) {
            int gr0 = ub * 32 + w * 8;
            #pragma unroll
            for (int i = 0; i < 8; ++i) u[gr0 + i] = sums[i];
        }
    }
}

// ---------------- scan (bid<64) + linear1 MFMA (bid in [64,320)) ----------------
__global__ __launch_bounds__(512) void scan_linear1_kernel(const int* __restrict__ idx1a,
                                                           const int* __restrict__ idx2a,
                                                           int* __restrict__ slot_token,
                                                           const unsigned short* __restrict__ Xbf,
                                                           const unsigned short* __restrict__ W1B,
                                                           const float* __restrict__ b1,
                                                           unsigned short* __restrict__ hbf) {
    __shared__ char smem[65536];
    const int tid = threadIdx.x;
    const int w = tid >> 6, l = tid & 63;
    if (blockIdx.x < 64) {                              // ======== scan ========
        const int bb = blockIdx.x;
        const int b = bb >> 4, e = bb & 15;
        int* cnt1 = (int*)smem;
        int* cnt2 = cnt1 + 8;
        int* slot = slot_token + (e * NB + b) * CAP;
        const unsigned long long below = (l == 0) ? 0ull : ((1ull << l) - 1ull);
        const int base0 = w * 256;
        int c1 = 0, c2 = 0;
        #pragma unroll
        for (int it = 0; it < 4; ++it) {
            int n = base0 + it * 64 + l;
            c1 += __popcll(__ballot(idx1a[b * NN + n] == e));
            c2 += __popcll(__ballot(idx2a[b * NN + n] == e));
        }
        if (l == 0) { cnt1[w] = c1; cnt2[w] = c2; }
        __syncthreads();
        int b1c = 0, t1 = 0, b2c = 0, t2 = 0;
        #pragma unroll
        for (int i = 0; i < 8; ++i) {
            int v1 = cnt1[i], v2 = cnt2[i];
            if (i < w) { b1c += v1; b2c += v2; }
            t1 += v1; t2 += v2;
        }
        const int start2 = (t1 < CAP) ? t1 : CAP;
        int c = b1c;
        #pragma unroll
        for (int it = 0; it < 4; ++it) {
            int n = base0 + it * 64 + l;
            bool p = (idx1a[b * NN + n] == e);
            unsigned long long m = __ballot(p);
            int pre = __popcll(m & below);
            if (p) { int pos = c + pre; if (pos < CAP) slot[pos] = n; }
            c += __popcll(m);
        }
        c = start2 + b2c;
        #pragma unroll
        for (int it = 0; it < 4; ++it) {
            int n = base0 + it * 64 + l;
            bool p = (idx2a[b * NN + n] == e);
            unsigned long long m = __ballot(p);
            int pre = __popcll(m & below);
            if (p) { int pos = c + pre; if (pos < CAP) slot[pos] = n | (1 << 30); }
            c += __popcll(m);
        }
        int nfill = start2 + t2; nfill = (nfill < CAP) ? nfill : CAP;
        for (int i = nfill + tid; i < CAP; i += 512) slot[i] = -1;
        return;
    }
    // ======== linear1 ========
    const int lb = blockIdx.x - 64;
    const int m0 = (lb >> 2) * 128, n0 = (lb & 3) * 128;
    const int wm = w >> 1, wn = w & 1;      // 4 x 2 wave grid, wave tile 32x64
    const int lr = l & 15, lk = l >> 4;
    char* Ash0 = smem;                      // 2 x 16384
    char* Bsh0 = smem + 32768;              // 2 x 16384

    auto stage = [&](int Ks, int buf) {
        #pragma unroll
        for (int i = 0; i < 2; ++i) {
            int o = i * 8192 + tid * 16;
            int r = o >> 7, bb = o & 127;
            int sb2 = bb ^ ((r & 7) << 4);
            gload16((const char*)Xbf + ((size_t)(m0 + r) * ND + Ks * 64) * 2 + sb2,
                    Ash0 + buf * 16384 + i * 8192 + w * 1024);
            gload16((const char*)W1B + ((size_t)(Ks * 512 + n0 + r) * 64) * 2 + sb2,
                    Bsh0 + buf * 16384 + i * 8192 + w * 1024);
        }
    };

    f32x4 acc[2][4] = {};
    stage(0, 0);
    __syncthreads();
    for (int Ks = 0; Ks < 8; ++Ks) {
        int buf = Ks & 1;
        if (Ks < 7) stage(Ks + 1, buf ^ 1);
        #pragma unroll
        for (int k32 = 0; k32 < 2; ++k32) {
            int kb = (k32 * 32 + 8 * lk) * 2;
            bf16x8 a[2], bfr[4];
            #pragma unroll
            for (int mi = 0; mi < 2; ++mi) {
                int row = wm * 32 + mi * 16 + lr;
                a[mi] = *(const bf16x8*)(Ash0 + buf * 16384 + row * 128 + (kb ^ ((row & 7) << 4)));
            }
            #pragma unroll
            for (int ni = 0; ni < 4; ++ni) {
                int row = wn * 64 + ni * 16 + lr;
                bfr[ni] = *(const bf16x8*)(Bsh0 + buf * 16384 + row * 128 + (kb ^ ((row & 7) << 4)));
            }
            #pragma unroll
            for (int mi = 0; mi < 2; ++mi)
                #pragma unroll
                for (int ni = 0; ni < 4; ++ni)
                    acc[mi][ni] = __builtin_amdgcn_mfma_f32_16x16x32_bf16(a[mi], bfr[ni], acc[mi][ni], 0, 0, 0);
        }
        __syncthreads();
    }
    #pragma unroll
    for (int mi = 0; mi < 2; ++mi)
        #pragma unroll
        for (int ni = 0; ni < 4; ++ni) {
            int col = n0 + wn * 64 + ni * 16 + lr;
            float bb1 = b1[col];
            #pragma unroll
            for (int r = 0; r < 4; ++r) {
                int m = m0 + wm * 32 + mi * 16 + lk * 4 + r;
                hbf[(size_t)m * ND + col] = f2bf(acc[mi][ni][r] + bb1);
            }
        }
}

// ---------------- expert MFMA v2: 64x64 wave tiles, BK=32, atomicAdd epilogue ----------------
__global__ __launch_bounds__(512) void expert_mfma_kernel(const unsigned short* __restrict__ hbf,
                                                          const unsigned short* __restrict__ We1B,
                                                          const float* __restrict__ u,
                                                          const int* __restrict__ slot_token,
                                                          const float* __restrict__ zbuf,
                                                          const float* __restrict__ g1a,
                                                          const float* __restrict__ g2a,
                                                          float* __restrict__ out) {
    __shared__ char Ash[65536];             // 64 slots x 512 k bf16, rows 1024B, XOR (row&7)<<4
    __shared__ char Bsh[2][32768];          // 512 h x 32 k bf16, rows 64B, XOR ((row>>1)&3)<<4
    __shared__ float u_lds[NH];
    __shared__ float sbuf[8][64];
    __shared__ int toks[64];
    const int tid = threadIdx.x;
    const int w = tid >> 6, l = tid & 63;
    const int lr = l & 15, lk = l >> 4;
    // XCD swizzle: all 16 blocks of an expert share an XCD (bid % 8 == e % 8)
    const int bid = blockIdx.x;
    const int e = (bid & 7) | ((bid >> 7) << 3);
    const int chunk = (bid >> 3) & 15;
    const int b = chunk >> 2, c0 = (chunk & 3) * 64;

    if (tid < 64) toks[tid] = slot_token[(e * NB + b) * CAP + c0 + tid];
    u_lds[tid] = u[e * NH + tid];
    u_lds[tid + 512] = u[e * NH + tid + 512];
    __syncthreads();
    // A gather: 64 token rows (full K), wave-uniform row, pre-swizzled source (rule #21)
    #pragma unroll
    for (int i = 0; i < 8; ++i) {
        int r = i * 8 + w;
        int t = toks[r];
        int tok = t & 2047;
        int sb = (l * 16) ^ ((r & 7) << 4);
        const char* src = (t >= 0) ? ((const char*)hbf + ((size_t)(b * NN + tok) * ND) * 2 + sb)
                                   : ((const char*)zbuf + sb);
        gload16(src, Ash + i * 8192 + w * 1024);
    }
    // B stage: (Hc, Ks) = 512 h x 32 k; linear dest, inverse-swizzled source
    auto stageB = [&](int s, int buf) {
        int Hc = s >> 4, Ks = s & 15;
        const size_t base = ((size_t)(e * 8 + (Ks >> 1)) * NH + Hc * 512) * 64 + (Ks & 1) * 32;
        #pragma unroll
        for (int i = 0; i < 4; ++i) {
            int r = i * 128 + w * 16 + (l >> 2);
            int swzr = ((r >> 1) & 3) << 4;
            int ebyte = ((l & 3) * 16) ^ swzr;          // bytes within the 64B row
            gload16((const char*)We1B + (base + (size_t)r * 64) * 2 + ebyte,
                    Bsh[buf] + i * 8192 + w * 1024);
        }
    };
    f32x4 acc[4][4] = {};
    float srow[4][4] = {};
    stageB(0, 0);
    __syncthreads();
    for (int s = 0; s < 32; ++s) {          // 2 Hc x 16 Ks
        int buf = s & 1;
        if (s < 31) stageB(s + 1, buf ^ 1);
        int Ks = s & 15;
        bf16x8 a[4], bb[4];
        #pragma unroll
        for (int mi = 0; mi < 4; ++mi) {
            int row = mi * 16 + lr;
            int kb = (Ks * 64 + lk * 16) ^ ((row & 7) << 4);
            a[mi] = *(const bf16x8*)(Ash + row * 1024 + kb);
        }
        #pragma unroll
        for (int ni = 0; ni < 4; ++ni) {
            int row = w * 64 + ni * 16 + lr;            // h row 0..511
            int kb = (lk * 16) ^ (((row >> 1) & 3) << 4);
            bb[ni] = *(const bf16x8*)(Bsh[buf] + row * 64 + kb);
        }
        #pragma unroll
        for (int mi = 0; mi < 4; ++mi)
            #pragma unroll
            for (int ni = 0; ni < 4; ++ni)
                acc[mi][ni] = __builtin_amdgcn_mfma_f32_16x16x32_bf16(a[mi], bb[ni], acc[mi][ni], 0, 0, 0);
        if ((s & 15) == 15) {               // Hc done: fold lrelu . u, reset acc
            int Hc = s >> 4;
            #pragma unroll
            for (int ni = 0; ni < 4; ++ni) {
                float uu = u_lds[Hc * 512 + w * 64 + ni * 16 + lr];
                #pragma unroll
                for (int mi = 0; mi < 4; ++mi)
                    #pragma unroll
                    for (int r = 0; r < 4; ++r) {
                        float x = acc[mi][ni][r];
                        x = (x > 0.f) ? x : 0.01f * x;
                        srow[mi][r] = fmaf(x, uu, srow[mi][r]);
                        acc[mi][ni][r] = 0.f;
                    }
            }
        }
        __syncthreads();
    }
    // reduce over the 16 col-lanes (lr), stash per-wave partials, then sum 8 waves
    #pragma unroll
    for (int off = 1; off < 16; off <<= 1)
        #pragma unroll
        for (int mi = 0; mi < 4; ++mi)
            #pragma unroll
            for (int r = 0; r < 4; ++r)
                srow[mi][r] += __shfl_xor(srow[mi][r], off);
    if (lr == 0) {
        #pragma unroll
        for (int mi = 0; mi < 4; ++mi)
            #pragma unroll
            for (int r = 0; r < 4; ++r)
                sbuf[w][mi * 16 + lk * 4 + r] = srow[mi][r];
    }
    __syncthreads();
    if (tid < 64) {
        float s = 0.f;
        #pragma unroll
        for (int q = 0; q < 8; ++q) s += sbuf[q][tid];
        int v = toks[tid];
        if (v >= 0) {
            int tok = v & 2047;
            float g = (v & (1 << 30)) ? g2a[b * NN + tok] : g1a[b * NN + tok];
            atomicAdd(out + b * NN + tok, s * g);
        }
    }
}

extern "C" void kernel_launch(void* const* d_in, const int* in_sizes, int n_in,
                              void* d_out, int out_size, void* d_ws, size_t ws_size,
                              hipStream_t stream) {
    const float* X    = (const float*)d_in[0];
    const float* probs= (const float*)d_in[1];
    const float* W1   = (const float*)d_in[2];
    const float* b1   = (const float*)d_in[3];
    const float* Wg   = (const float*)d_in[4];
    const float* We1  = (const float*)d_in[5];
    const float* We2  = (const float*)d_in[6];
    const float* W3   = (const float*)d_in[7];
    const float* b3   = (const float*)d_in[8];
    const float* W4   = (const float*)d_in[9];
    const float* b4   = (const float*)d_in[10];
    float* out = (float*)d_out;

    char* ws = (char*)d_ws;
    size_t off = 0;
    auto alloc = [&](size_t bytes) { void* p = ws + off; off += (bytes + 255) & ~(size_t)255; return p; };
    unsigned short* Xbf  = (unsigned short*)alloc((size_t)NTOK * ND * 2);     // 8 MB
    unsigned short* hbf  = (unsigned short*)alloc((size_t)NTOK * ND * 2);     // 8 MB
    unsigned short* W1B  = (unsigned short*)alloc((size_t)ND * ND * 2);       // 512 KB
    unsigned short* We1B = (unsigned short*)alloc((size_t)NE * NH * ND * 2);  // 16 MB
    float* WcT     = (float*)alloc(NE * ND * 4);
    float* u       = (float*)alloc(NE * NH * 4);
    float* zbuf    = (float*)alloc(1024);
    int*   idx1a   = (int*)alloc(NTOK * 4);
    int*   idx2a   = (int*)alloc(NTOK * 4);
    float* g1a     = (float*)alloc(NTOK * 4);
    float* g2a     = (float*)alloc(NTOK * 4);
    int*   slot_tok= (int*)alloc(NE * NB * CAP * 4);
    (void)ws_size; (void)in_sizes; (void)n_in; (void)out_size;

    prep_w_kernel<<<144, 256, 0, stream>>>(W1, Wg, W1B, WcT, zbuf);
    gating_stream_kernel<<<1536, 256, 0, stream>>>(X, WcT, probs, b3, W4, b4,
                                                   We1, We2, W3,
                                                   Xbf, We1B, u,
                                                   idx1a, idx2a, g1a, g2a, out);
    scan_linear1_kernel<<<320, 512, 0, stream>>>(idx1a, idx2a, slot_tok,
                                                 Xbf, W1B, b1, hbf);
    expert_mfma_kernel<<<256, 512, 0, stream>>>(hbf, We1B, u, slot_tok, zbuf, g1a, g2a, out);
}